// Round 7
// baseline (521.783 us; speedup 1.0000x reference)
//
#include <hip/hip_runtime.h>
#include <cstdint>
#include <cstddef>

#define B_ 16
#define C_ 64
#define N_ 2048
#define K_ 20
#define TM2 128
#define L 7
#define CANDH 22
#define CAND_T 44

__device__ __forceinline__ unsigned umin_(unsigned a, unsigned b) { return a < b ? a : b; }
__device__ __forceinline__ unsigned umax_(unsigned a, unsigned b) { return a > b ? a : b; }

// K1: sqf = np.sum(xt*xt,-1) replicated bit-exactly (pairwise 8-acc tree).
__global__ __launch_bounds__(256) void k_sq(const float* __restrict__ x,
                                            float* __restrict__ sqf) {
    int i = blockIdx.x * 256 + threadIdx.x;   // 0..B_*N_-1
    int b = i >> 11, n = i & (N_ - 1);
    const float* xb = x + (size_t)b * C_ * N_ + n;
    float p[C_];
#pragma unroll
    for (int c = 0; c < C_; ++c) {
        float v = xb[(size_t)c * N_];
        p[c] = __fmul_rn(v, v);
    }
    float r[8];
#pragma unroll
    for (int k = 0; k < 8; ++k) r[k] = p[k];
#pragma unroll
    for (int ii = 8; ii < 64; ii += 8) {
#pragma unroll
        for (int k = 0; k < 8; ++k) r[k] = __fadd_rn(r[k], p[ii + k]);
    }
    float s0 = __fadd_rn(__fadd_rn(r[0], r[1]), __fadd_rn(r[2], r[3]));
    float s1 = __fadd_rn(__fadd_rn(r[4], r[5]), __fadd_rn(r[6], r[7]));
    sqf[i] = __fadd_rn(s0, s1);
}

// K3: Yt[b][m][o] = sum_c (W[o][c] - W[o][64+c]) * x[b][c][m]
__global__ __launch_bounds__(256) void k_y(const float* __restrict__ x,
                                           const float* __restrict__ W,
                                           float* __restrict__ Yt) {
    __shared__ float Al[C_ * 64];  // [c][o]
    __shared__ float xl[C_ * 64];  // [c][m]
    int tid = threadIdx.x;
    int bid = blockIdx.x;
    int b = bid >> 5;
    int m0 = (bid & 31) * 64;
    {
        int o = tid & 63, cb = tid >> 6;
#pragma unroll
        for (int j = 0; j < 16; ++j) {
            int c = cb * 16 + j;
            Al[c * 64 + o] = W[o * 128 + c] - W[o * 128 + 64 + c];
            xl[c * 64 + o] = x[((size_t)b * C_ + c) * N_ + m0 + o];
        }
    }
    __syncthreads();
    int ml = tid & 63, og = tid >> 6;
    float acc[16];
#pragma unroll
    for (int j = 0; j < 16; ++j) acc[j] = 0.f;
#pragma unroll 4
    for (int c = 0; c < C_; ++c) {
        float xv = xl[c * 64 + ml];
        const float4* a4 = reinterpret_cast<const float4*>(&Al[c * 64 + og * 16]);
#pragma unroll
        for (int q = 0; q < 4; ++q) {
            float4 av = a4[q];
            acc[q * 4 + 0] = fmaf(av.x, xv, acc[q * 4 + 0]);
            acc[q * 4 + 1] = fmaf(av.y, xv, acc[q * 4 + 1]);
            acc[q * 4 + 2] = fmaf(av.z, xv, acc[q * 4 + 2]);
            acc[q * 4 + 3] = fmaf(av.w, xv, acc[q * 4 + 3]);
        }
    }
    float* yp = Yt + ((size_t)b * N_ + m0 + ml) * C_ + og * 16;
#pragma unroll
    for (int q = 0; q < 4; ++q) {
        reinterpret_cast<float4*>(yp)[q] =
            make_float4(acc[q * 4 + 0], acc[q * 4 + 1], acc[q * 4 + 2], acc[q * 4 + 3]);
    }
}

// K2a: fast distance pass, m-split x2 for occupancy. Block = 64 rows x 1024 ms
// (8 waves x 8 rows; 8 tiles of 128). Rows in LDS (uniform broadcast reads);
// per-lane sorted top-L of fixed-point keys (d*2048 quant | m); extraction:
// 22 wave-min rounds per row, ILP'd 4 rows at a time.
__global__ __launch_bounds__(512) void k_dist(const float* __restrict__ x,
                                              const float* __restrict__ sqf,
                                              unsigned short* __restrict__ cand) {
    __shared__ float xt[TM2][68];     // 272B rows: 16B-aligned b128, ~free phases
    __shared__ float rowsl[64][64];   // unpadded: wave-uniform broadcast reads
    int tid = threadIdx.x;
    int w = tid >> 6, lane = tid & 63;
    int bid = blockIdx.x;             // B_*64 = 1024
    int b = bid >> 6;
    int g = bid & 63;
    int rowgrp = g >> 1, half = g & 1;
    int n0 = rowgrp * 64;
    int mbase = half * 1024;
    const float* xb = x + (size_t)b * C_ * N_;

    {   // stage 64 rows: wave w stages c = w*8 .. w*8+7 (coalesced per c)
#pragma unroll
        for (int j = 0; j < 8; ++j) {
            int c = w * 8 + j;
            rowsl[lane][c] = xb[(size_t)c * N_ + n0 + lane];
        }
    }
    float rsq[8];
#pragma unroll
    for (int r = 0; r < 8; ++r) rsq[r] = sqf[b * N_ + n0 + w * 8 + r];

    unsigned list[8][L];
#pragma unroll
    for (int r = 0; r < 8; ++r)
#pragma unroll
        for (int j = 0; j < L; ++j) list[r][j] = 0xFFFFFFFFu;

    for (int t = 0; t < 8; ++t) {
        int m0 = mbase + t * TM2;
        __syncthreads();
        {   // stage m-tile (coalesced per c)
            int u = tid >> 7, ml = tid & 127;
#pragma unroll
            for (int cb = 0; cb < 4; ++cb) {
                int c = u * 16 + cb * 4;
                float4 v;
                v.x = xb[(size_t)(c + 0) * N_ + m0 + ml];
                v.y = xb[(size_t)(c + 1) * N_ + m0 + ml];
                v.z = xb[(size_t)(c + 2) * N_ + m0 + ml];
                v.w = xb[(size_t)(c + 3) * N_ + m0 + ml];
                *reinterpret_cast<float4*>(&xt[ml][c]) = v;
            }
        }
        __syncthreads();

        // opaque row index: stop LICM from hoisting row reads out of the loop
        int rb = w * 8;
        asm volatile("" : "+v"(rb));

        float acc[8][2];
#pragma unroll
        for (int r = 0; r < 8; ++r) { acc[r][0] = 0.f; acc[r][1] = 0.f; }
#pragma unroll 2
        for (int cc = 0; cc < 16; ++cc) {
            float4 xv0 = *reinterpret_cast<const float4*>(&xt[lane][cc * 4]);
            float4 xv1 = *reinterpret_cast<const float4*>(&xt[64 + lane][cc * 4]);
#pragma unroll
            for (int r = 0; r < 8; ++r) {
                float4 rv = *reinterpret_cast<const float4*>(&rowsl[rb + r][cc * 4]);
                acc[r][0] = fmaf(rv.x, xv0.x, acc[r][0]);
                acc[r][0] = fmaf(rv.y, xv0.y, acc[r][0]);
                acc[r][0] = fmaf(rv.z, xv0.z, acc[r][0]);
                acc[r][0] = fmaf(rv.w, xv0.w, acc[r][0]);
                acc[r][1] = fmaf(rv.x, xv1.x, acc[r][1]);
                acc[r][1] = fmaf(rv.y, xv1.y, acc[r][1]);
                acc[r][1] = fmaf(rv.z, xv1.z, acc[r][1]);
                acc[r][1] = fmaf(rv.w, xv1.w, acc[r][1]);
            }
        }
        float sm0 = sqf[b * N_ + m0 + lane];
        float sm1 = sqf[b * N_ + m0 + 64 + lane];
#pragma unroll
        for (int s = 0; s < 2; ++s) {
            float sm = s ? sm1 : sm0;
            unsigned m = (unsigned)(m0 + s * 64 + lane);
#pragma unroll
            for (int r = 0; r < 8; ++r) {
                float d = (rsq[r] + sm) - 2.f * acc[r][s];
                // fixed-point key: step 1/2048 (quant err ~5e-4 << rank gaps)
                float dq = fminf(fmaxf(d, 0.f) * 2048.0f, 1048575.0f);
                unsigned key = ((unsigned)dq << 11) | m;
#pragma unroll
                for (int j = L - 1; j > 0; --j)
                    list[r][j] = umin_(list[r][j], umax_(list[r][j - 1], key));
                list[r][0] = umin_(list[r][0], key);
            }
        }
    }

    // extraction: 22 rounds of wave-min per row; 4 rows in flight for ILP.
    // keys unique (low 11 bits = m, m%64 = lane) -> exactly one owner pops.
#pragma unroll
    for (int grp = 0; grp < 2; ++grp) {
        unsigned myex[4];
#pragma unroll
        for (int r2 = 0; r2 < 4; ++r2) myex[r2] = 0u;
#pragma unroll 1
        for (int it = 0; it < CANDH; ++it) {
            unsigned head[4], wv[4];
#pragma unroll
            for (int r2 = 0; r2 < 4; ++r2) {
                head[r2] = list[grp * 4 + r2][0];
                wv[r2] = head[r2];
            }
#pragma unroll
            for (int d2 = 1; d2 < 64; d2 <<= 1)
#pragma unroll
                for (int r2 = 0; r2 < 4; ++r2)
                    wv[r2] = umin_(wv[r2], (unsigned)__shfl_xor((int)wv[r2], d2, 64));
#pragma unroll
            for (int r2 = 0; r2 < 4; ++r2) {
                bool own = (head[r2] == wv[r2]);
#pragma unroll
                for (int j = 0; j < L - 1; ++j)
                    list[grp * 4 + r2][j] = own ? list[grp * 4 + r2][j + 1]
                                                : list[grp * 4 + r2][j];
                list[grp * 4 + r2][L - 1] = own ? 0xFFFFFFFFu : list[grp * 4 + r2][L - 1];
                myex[r2] = (lane == it) ? (wv[r2] & 2047u) : myex[r2];
            }
        }
#pragma unroll
        for (int r2 = 0; r2 < 4; ++r2) {
            size_t grow = (size_t)b * N_ + n0 + w * 8 + grp * 4 + r2;
            if (lane < CANDH)
                cand[grow * CAND_T + half * CANDH + lane] = (unsigned short)myex[r2];
        }
    }
}

// K2b: exact numpy-f32 rescore (sequential c, separate mul/add, strided x —
// bit-identical to round-3's proven form) + stable rank over 44 candidates.
__global__ __launch_bounds__(256) void k_rescore(const float* __restrict__ x,
                                                 const float* __restrict__ sqf,
                                                 const unsigned short* __restrict__ cand,
                                                 float* __restrict__ idxf) {
    int tid = threadIdx.x;
    int w = tid >> 6, lane = tid & 63;
    size_t grow = (size_t)blockIdx.x * 4 + w;   // 0..32767
    int b = (int)(grow >> 11), n = (int)(grow & (N_ - 1));
    const float* xb = x + (size_t)b * C_ * N_;
    float d = 0.f;
    unsigned m = 0xFFFFFFFFu;
    if (lane < CAND_T) {
        m = cand[grow * CAND_T + lane];
        float a = 0.f;
#pragma unroll 8
        for (int c = 0; c < C_; ++c)
            a = __fadd_rn(a, __fmul_rn(xb[(size_t)c * N_ + n], xb[(size_t)c * N_ + m]));
        d = __fadd_rn(__fsub_rn(sqf[b * N_ + n], __fmul_rn(2.0f, a)), sqf[b * N_ + m]);
    }
    int rank = 0;
#pragma unroll 1
    for (int j = 0; j < CAND_T; ++j) {
        float dj = __shfl(d, j, 64);
        unsigned mj = (unsigned)__shfl((int)m, j, 64);
        if (lane < CAND_T && (dj < d || (dj == d && mj < m))) ++rank;
    }
    if (lane < CAND_T && rank < K_)
        idxf[grow * K_ + rank] = (float)m;
}

// K4: out[b][o][n] = leaky( s[o]*(u + max_k Yt[b][idx[n][k]][o]) + t[o] )
__global__ __launch_bounds__(256) void k_out(const float* __restrict__ x,
                                             const float* __restrict__ W,
                                             const float* __restrict__ gamma,
                                             const float* __restrict__ beta,
                                             const float* __restrict__ rmean,
                                             const float* __restrict__ rvar,
                                             const float* __restrict__ Yt,
                                             const float* __restrict__ idxf,
                                             float* __restrict__ out) {
    __shared__ float Bl[C_ * 64];
    __shared__ float xl[C_ * 64];
    __shared__ float resl[64 * 65];
    __shared__ float sl[64], tl[64];
    int tid = threadIdx.x;
    int bid = blockIdx.x;
    int b = bid >> 5;
    int n0 = (bid & 31) * 64;
    {
        int o = tid & 63, cb = tid >> 6;
#pragma unroll
        for (int j = 0; j < 16; ++j) {
            int c = cb * 16 + j;
            Bl[c * 64 + o] = W[o * 128 + 64 + c];
            xl[c * 64 + o] = x[((size_t)b * C_ + c) * N_ + n0 + o];
        }
        if (tid < 64) {
            float s = gamma[tid] / sqrtf(rvar[tid] + 1e-5f);
            sl[tid] = s;
            tl[tid] = beta[tid] - rmean[tid] * s;
        }
    }
    __syncthreads();
    int w = tid >> 6, o = tid & 63;
    for (int i = 0; i < 16; ++i) {
        int nl = w * 16 + i;
        int n = n0 + nl;
        float u = 0.f;
#pragma unroll 8
        for (int c = 0; c < C_; ++c)
            u = fmaf(Bl[c * 64 + o], xl[c * 64 + nl], u);
        const float* ip = idxf + ((size_t)b * N_ + n) * K_;
        float v = -3.4e38f;
#pragma unroll
        for (int k = 0; k < K_; ++k) {
            int mi = (int)ip[k];
            v = fmaxf(v, Yt[((size_t)b * N_ + mi) * C_ + o]);
        }
        float h = u + v;
        float val = sl[o] * h + tl[o];
        val = val > 0.f ? val : 0.2f * val;
        resl[o * 65 + nl] = val;
    }
    __syncthreads();
    {
        int nl = tid & 63, ob = tid >> 6;
#pragma unroll
        for (int j = 0; j < 16; ++j) {
            int o2 = ob * 16 + j;
            out[((size_t)b * C_ + o2) * N_ + n0 + nl] = resl[o2 * 65 + nl];
        }
    }
}

extern "C" void kernel_launch(void* const* d_in, const int* in_sizes, int n_in,
                              void* d_out, int out_size, void* d_ws, size_t ws_size,
                              hipStream_t stream) {
    const float* x     = (const float*)d_in[0];
    const float* W     = (const float*)d_in[1];
    const float* gamma = (const float*)d_in[2];
    const float* beta  = (const float*)d_in[3];
    const float* rmean = (const float*)d_in[4];
    const float* rvar  = (const float*)d_in[5];

    float* out  = (float*)d_out;                         // [16][64][2048]
    float* idxf = out + (size_t)B_ * C_ * N_;            // [16][2048][20] as floats

    char* ws             = (char*)d_ws;
    float* sqf           = (float*)ws;                   // 128 KB
    unsigned short* cand = (unsigned short*)(ws + 131072);          // 2.88 MB
    float* Yt            = (float*)(ws + 131072 + 2883584);         // 8 MB

    k_sq     <<<B_ * N_ / 256, 256, 0, stream>>>(x, sqf);
    k_y      <<<B_ * (N_ / 64), 256, 0, stream>>>(x, W, Yt);
    k_dist   <<<B_ * 64, 512, 0, stream>>>(x, sqf, cand);
    k_rescore<<<B_ * N_ / 4, 256, 0, stream>>>(x, sqf, cand, idxf);
    k_out    <<<B_ * (N_ / 64), 256, 0, stream>>>(x, W, gamma, beta, rmean, rvar, Yt, idxf, out);
}

// Round 8
// 486.897 us; speedup vs baseline: 1.0717x; 1.0717x over previous
//
#include <hip/hip_runtime.h>
#include <cstdint>
#include <cstddef>

#define B_ 16
#define C_ 64
#define N_ 2048
#define K_ 20
#define TM3 64
#define RW 4
#define L 7
#define CAND 24

__device__ __forceinline__ unsigned umin_(unsigned a, unsigned b) { return a < b ? a : b; }
__device__ __forceinline__ unsigned umax_(unsigned a, unsigned b) { return a > b ? a : b; }

// K1: sqf = np.sum(xt*xt,-1) replicated bit-exactly (pairwise 8-acc tree),
// plus transposed copy xrT[b][n][c] = x[b][c][n] for k_rescore's contiguous rows.
__global__ __launch_bounds__(128) void k_sq(const float* __restrict__ x,
                                            float* __restrict__ sqf,
                                            float* __restrict__ xrT) {
    int i = blockIdx.x * 128 + threadIdx.x;   // 0..B_*N_-1
    int b = i >> 11, n = i & (N_ - 1);
    const float* xb = x + (size_t)b * C_ * N_ + n;
    float vr[C_];
#pragma unroll
    for (int c = 0; c < C_; ++c) vr[c] = xb[(size_t)c * N_];
    float p[C_];
#pragma unroll
    for (int c = 0; c < C_; ++c) p[c] = __fmul_rn(vr[c], vr[c]);
    float r[8];
#pragma unroll
    for (int k = 0; k < 8; ++k) r[k] = p[k];
#pragma unroll
    for (int ii = 8; ii < 64; ii += 8) {
#pragma unroll
        for (int k = 0; k < 8; ++k) r[k] = __fadd_rn(r[k], p[ii + k]);
    }
    float s0 = __fadd_rn(__fadd_rn(r[0], r[1]), __fadd_rn(r[2], r[3]));
    float s1 = __fadd_rn(__fadd_rn(r[4], r[5]), __fadd_rn(r[6], r[7]));
    sqf[i] = __fadd_rn(s0, s1);
    float4* dst = reinterpret_cast<float4*>(xrT + (size_t)i * C_);
#pragma unroll
    for (int q = 0; q < 16; ++q)
        dst[q] = make_float4(vr[q * 4 + 0], vr[q * 4 + 1], vr[q * 4 + 2], vr[q * 4 + 3]);
}

// K3: Yt[b][m][o] = sum_c (W[o][c] - W[o][64+c]) * x[b][c][m]
__global__ __launch_bounds__(256) void k_y(const float* __restrict__ x,
                                           const float* __restrict__ W,
                                           float* __restrict__ Yt) {
    __shared__ float Al[C_ * 64];  // [c][o]
    __shared__ float xl[C_ * 64];  // [c][m]
    int tid = threadIdx.x;
    int bid = blockIdx.x;
    int b = bid >> 5;
    int m0 = (bid & 31) * 64;
    {
        int o = tid & 63, cb = tid >> 6;
#pragma unroll
        for (int j = 0; j < 16; ++j) {
            int c = cb * 16 + j;
            Al[c * 64 + o] = W[o * 128 + c] - W[o * 128 + 64 + c];
            xl[c * 64 + o] = x[((size_t)b * C_ + c) * N_ + m0 + o];
        }
    }
    __syncthreads();
    int ml = tid & 63, og = tid >> 6;
    float acc[16];
#pragma unroll
    for (int j = 0; j < 16; ++j) acc[j] = 0.f;
#pragma unroll 4
    for (int c = 0; c < C_; ++c) {
        float xv = xl[c * 64 + ml];
        const float4* a4 = reinterpret_cast<const float4*>(&Al[c * 64 + og * 16]);
#pragma unroll
        for (int q = 0; q < 4; ++q) {
            float4 av = a4[q];
            acc[q * 4 + 0] = fmaf(av.x, xv, acc[q * 4 + 0]);
            acc[q * 4 + 1] = fmaf(av.y, xv, acc[q * 4 + 1]);
            acc[q * 4 + 2] = fmaf(av.z, xv, acc[q * 4 + 2]);
            acc[q * 4 + 3] = fmaf(av.w, xv, acc[q * 4 + 3]);
        }
    }
    float* yp = Yt + ((size_t)b * N_ + m0 + ml) * C_ + og * 16;
#pragma unroll
    for (int q = 0; q < 4; ++q) {
        reinterpret_cast<float4*>(yp)[q] =
            make_float4(acc[q * 4 + 0], acc[q * 4 + 1], acc[q * 4 + 2], acc[q * 4 + 3]);
    }
}

// K2a: fast distance pass. 32 rows/block (8 waves x 4 rows), full m-range in
// 32 tiles of 64; rows in LDS (uniform broadcast b128); per-lane sorted top-L
// of masked-float keys; 24 wave-min extraction rounds per row (serial, TLP
// hides latency at 4 blocks/CU). LDS 25.3KB + VGPR<=64 -> 32 waves/CU.
__global__ __launch_bounds__(512, 8) void k_dist(const float* __restrict__ x,
                                                 const float* __restrict__ sqf,
                                                 unsigned* __restrict__ cand) {
    __shared__ float xt[TM3][66];     // stride 264B: proven ~conflict-free
    __shared__ float rowsl[32][66];   // padded: staging writes 2-way (free)
    int tid = threadIdx.x;
    int w = tid >> 6, lane = tid & 63;
    int bid = blockIdx.x;             // B_*64 = 1024
    int b = bid >> 6;
    int n0 = (bid & 63) * 32;
    const float* xb = x + (size_t)b * C_ * N_;

    {   // stage 32 rows (coalesced in 32-lane groups per c)
        int i = tid & 31, u = tid >> 5;   // u: 0..15
#pragma unroll
        for (int j = 0; j < 4; ++j) {
            int c = u * 4 + j;
            rowsl[i][c] = xb[(size_t)c * N_ + n0 + i];
        }
    }
    float rsq[RW];
#pragma unroll
    for (int r = 0; r < RW; ++r) rsq[r] = sqf[b * N_ + n0 + w * RW + r];

    unsigned list[RW][L];
#pragma unroll
    for (int r = 0; r < RW; ++r)
#pragma unroll
        for (int j = 0; j < L; ++j) list[r][j] = 0xFFFFFFFFu;

    for (int t = 0; t < N_ / TM3; ++t) {
        int m0 = t * TM3;
        __syncthreads();
        {   // stage m-tile: thread owns m = tid&63, c = (tid>>6)*8 .. +7
            int u = tid >> 6, ml = tid & 63;
            int c0 = u * 8;
            float4 v0, v1;
            v0.x = xb[(size_t)(c0 + 0) * N_ + m0 + ml];
            v0.y = xb[(size_t)(c0 + 1) * N_ + m0 + ml];
            v0.z = xb[(size_t)(c0 + 2) * N_ + m0 + ml];
            v0.w = xb[(size_t)(c0 + 3) * N_ + m0 + ml];
            v1.x = xb[(size_t)(c0 + 4) * N_ + m0 + ml];
            v1.y = xb[(size_t)(c0 + 5) * N_ + m0 + ml];
            v1.z = xb[(size_t)(c0 + 6) * N_ + m0 + ml];
            v1.w = xb[(size_t)(c0 + 7) * N_ + m0 + ml];
            *reinterpret_cast<float4*>(&xt[ml][c0]) = v0;
            *reinterpret_cast<float4*>(&xt[ml][c0 + 4]) = v1;
        }
        __syncthreads();

        // opaque row index: stop LICM from hoisting row reads out of the loop
        int rb = w * RW;
        asm volatile("" : "+v"(rb));

        float acc[RW];
#pragma unroll
        for (int r = 0; r < RW; ++r) acc[r] = 0.f;
#pragma unroll 2
        for (int cc = 0; cc < 16; ++cc) {
            float4 xv = *reinterpret_cast<const float4*>(&xt[lane][cc * 4]);
#pragma unroll
            for (int r = 0; r < RW; ++r) {
                float4 rv = *reinterpret_cast<const float4*>(&rowsl[rb + r][cc * 4]);
                acc[r] = fmaf(rv.x, xv.x, acc[r]);
                acc[r] = fmaf(rv.y, xv.y, acc[r]);
                acc[r] = fmaf(rv.z, xv.z, acc[r]);
                acc[r] = fmaf(rv.w, xv.w, acc[r]);
            }
        }
        float sm = sqf[b * N_ + m0 + lane];
        unsigned m = (unsigned)(m0 + lane);
#pragma unroll
        for (int r = 0; r < RW; ++r) {
            float d = (rsq[r] + sm) - 2.f * acc[r];
            unsigned ub = __float_as_uint(d);
            unsigned mono = (ub & 0x80000000u) ? ~ub : (ub | 0x80000000u);
            unsigned key = (mono & 0xFFFFF800u) | m;
            // branchless sorted insert (ascending, list[0]=min)
#pragma unroll
            for (int j = L - 1; j > 0; --j)
                list[r][j] = umin_(list[r][j], umax_(list[r][j - 1], key));
            list[r][0] = umin_(list[r][0], key);
        }
    }

    // extraction: per row, 24 rounds of wave-min over sorted heads.
    // keys unique (low 11 bits = m, m%64 = lane) -> exactly one owner pops.
#pragma unroll
    for (int r = 0; r < RW; ++r) {
        size_t grow = (size_t)b * N_ + n0 + w * RW + r;
        unsigned myex = 0u;
#pragma unroll 1
        for (int it = 0; it < CAND; ++it) {
            unsigned head = list[r][0];
            unsigned wv = head;
#pragma unroll
            for (int d2 = 1; d2 < 64; d2 <<= 1)
                wv = umin_(wv, (unsigned)__shfl_xor((int)wv, d2, 64));
            bool own = (head == wv);
#pragma unroll
            for (int j = 0; j < L - 1; ++j)
                list[r][j] = own ? list[r][j + 1] : list[r][j];
            list[r][L - 1] = own ? 0xFFFFFFFFu : list[r][L - 1];
            myex = (lane == it) ? (wv & 2047u) : myex;
        }
        if (lane < CAND) cand[grow * CAND + lane] = myex;
    }
}

// K2b: exact numpy-f32 rescore (sequential c, separate mul/add) + stable rank.
// Uses contiguous xrT rows: identical values & order to round-3's proven form.
__global__ __launch_bounds__(256) void k_rescore(const float* __restrict__ xrT,
                                                 const float* __restrict__ sqf,
                                                 const unsigned* __restrict__ cand,
                                                 float* __restrict__ idxf) {
    int tid = threadIdx.x;
    int w = tid >> 6, lane = tid & 63;
    size_t grow = (size_t)blockIdx.x * 4 + w;   // 0..32767
    int b = (int)(grow >> 11), n = (int)(grow & (N_ - 1));
    const float* xr = xrT + (size_t)b * N_ * C_;
    const float* xn = xr + (size_t)n * C_;
    float d = 0.f;
    unsigned m = 0xFFFFFFFFu;
    if (lane < CAND) {
        m = cand[grow * CAND + lane];
        const float* xm = xr + (size_t)m * C_;
        float a = 0.f;
#pragma unroll 8
        for (int c = 0; c < C_; ++c)
            a = __fadd_rn(a, __fmul_rn(xn[c], xm[c]));
        d = __fadd_rn(__fsub_rn(sqf[b * N_ + n], __fmul_rn(2.0f, a)), sqf[b * N_ + m]);
    }
    int rank = 0;
#pragma unroll 1
    for (int j = 0; j < CAND; ++j) {
        float dj = __shfl(d, j, 64);
        unsigned mj = (unsigned)__shfl((int)m, j, 64);
        if (lane < CAND && (dj < d || (dj == d && mj < m))) ++rank;
    }
    if (lane < CAND && rank < K_)
        idxf[grow * K_ + rank] = (float)m;
}

// K4: out[b][o][n] = leaky( s[o]*(u + max_k Yt[b][idx[n][k]][o]) + t[o] )
__global__ __launch_bounds__(256) void k_out(const float* __restrict__ x,
                                             const float* __restrict__ W,
                                             const float* __restrict__ gamma,
                                             const float* __restrict__ beta,
                                             const float* __restrict__ rmean,
                                             const float* __restrict__ rvar,
                                             const float* __restrict__ Yt,
                                             const float* __restrict__ idxf,
                                             float* __restrict__ out) {
    __shared__ float Bl[C_ * 64];
    __shared__ float xl[C_ * 64];
    __shared__ float resl[64 * 65];
    __shared__ float sl[64], tl[64];
    int tid = threadIdx.x;
    int bid = blockIdx.x;
    int b = bid >> 5;
    int n0 = (bid & 31) * 64;
    {
        int o = tid & 63, cb = tid >> 6;
#pragma unroll
        for (int j = 0; j < 16; ++j) {
            int c = cb * 16 + j;
            Bl[c * 64 + o] = W[o * 128 + 64 + c];
            xl[c * 64 + o] = x[((size_t)b * C_ + c) * N_ + n0 + o];
        }
        if (tid < 64) {
            float s = gamma[tid] / sqrtf(rvar[tid] + 1e-5f);
            sl[tid] = s;
            tl[tid] = beta[tid] - rmean[tid] * s;
        }
    }
    __syncthreads();
    int w = tid >> 6, o = tid & 63;
    for (int i = 0; i < 16; ++i) {
        int nl = w * 16 + i;
        int n = n0 + nl;
        float u = 0.f;
#pragma unroll 8
        for (int c = 0; c < C_; ++c)
            u = fmaf(Bl[c * 64 + o], xl[c * 64 + nl], u);
        const float* ip = idxf + ((size_t)b * N_ + n) * K_;
        float v = -3.4e38f;
#pragma unroll
        for (int k = 0; k < K_; ++k) {
            int mi = (int)ip[k];
            v = fmaxf(v, Yt[((size_t)b * N_ + mi) * C_ + o]);
        }
        float h = u + v;
        float val = sl[o] * h + tl[o];
        val = val > 0.f ? val : 0.2f * val;
        resl[o * 65 + nl] = val;
    }
    __syncthreads();
    {
        int nl = tid & 63, ob = tid >> 6;
#pragma unroll
        for (int j = 0; j < 16; ++j) {
            int o2 = ob * 16 + j;
            out[((size_t)b * C_ + o2) * N_ + n0 + nl] = resl[o2 * 65 + nl];
        }
    }
}

extern "C" void kernel_launch(void* const* d_in, const int* in_sizes, int n_in,
                              void* d_out, int out_size, void* d_ws, size_t ws_size,
                              hipStream_t stream) {
    const float* x     = (const float*)d_in[0];
    const float* W     = (const float*)d_in[1];
    const float* gamma = (const float*)d_in[2];
    const float* beta  = (const float*)d_in[3];
    const float* rmean = (const float*)d_in[4];
    const float* rvar  = (const float*)d_in[5];

    float* out  = (float*)d_out;                         // [16][64][2048]
    float* idxf = out + (size_t)B_ * C_ * N_;            // [16][2048][20] as floats

    char* ws       = (char*)d_ws;
    float* sqf     = (float*)ws;                         // 128 KB
    unsigned* cand = (unsigned*)(ws + 131072);           // 3.1 MB
    float* xrT     = (float*)(ws + 131072 + 3145728);    // 8 MB
    float* Yt      = xrT;  // aliases xrT: xrT dead after k_rescore, Yt born at k_y

    k_sq     <<<B_ * N_ / 128, 128, 0, stream>>>(x, sqf, xrT);
    k_dist   <<<B_ * 64, 512, 0, stream>>>(x, sqf, cand);
    k_rescore<<<B_ * N_ / 4, 256, 0, stream>>>(xrT, sqf, cand, idxf);
    k_y      <<<B_ * (N_ / 64), 256, 0, stream>>>(x, W, Yt);
    k_out    <<<B_ * (N_ / 64), 256, 0, stream>>>(x, W, gamma, beta, rmean, rvar, Yt, idxf, out);
}

// Round 9
// 194.010 us; speedup vs baseline: 2.6895x; 2.5096x over previous
//
#include <hip/hip_runtime.h>
#include <cstdint>
#include <cstddef>

#define B_ 16
#define C_ 64
#define N_ 2048
#define K_ 20
#define CAND 24
#define LQ 12

typedef short bf16x8 __attribute__((ext_vector_type(8)));
typedef float f32x4 __attribute__((ext_vector_type(4)));

__device__ __forceinline__ unsigned umin_(unsigned a, unsigned b) { return a < b ? a : b; }
__device__ __forceinline__ unsigned umax_(unsigned a, unsigned b) { return a > b ? a : b; }
__device__ __forceinline__ unsigned short bfr_(float v) {
    unsigned u = __float_as_uint(v);
    return (unsigned short)((u + 0x7FFFu + ((u >> 16) & 1u)) >> 16);
}

// K1: sqf = np.sum(xt*xt,-1) bit-exact (pairwise 8-acc tree);
// xh[b][n] = bf16 row with c-blocks XOR-swizzled (block cb at slot cb^(n&7));
// xrT (optional) = f32 contiguous rows for exact rescore.
__global__ __launch_bounds__(128) void k_sq(const float* __restrict__ x,
                                            float* __restrict__ sqf,
                                            unsigned short* __restrict__ xh,
                                            float* __restrict__ xrT) {
    int i = blockIdx.x * 128 + threadIdx.x;   // 0..B_*N_-1
    int b = i >> 11, n = i & (N_ - 1);
    const float* xb = x + (size_t)b * C_ * N_ + n;
    float vr[C_];
#pragma unroll
    for (int c = 0; c < C_; ++c) vr[c] = xb[(size_t)c * N_];
    float p[C_];
#pragma unroll
    for (int c = 0; c < C_; ++c) p[c] = __fmul_rn(vr[c], vr[c]);
    float r[8];
#pragma unroll
    for (int k = 0; k < 8; ++k) r[k] = p[k];
#pragma unroll
    for (int ii = 8; ii < 64; ii += 8) {
#pragma unroll
        for (int k = 0; k < 8; ++k) r[k] = __fadd_rn(r[k], p[ii + k]);
    }
    float s0 = __fadd_rn(__fadd_rn(r[0], r[1]), __fadd_rn(r[2], r[3]));
    float s1 = __fadd_rn(__fadd_rn(r[4], r[5]), __fadd_rn(r[6], r[7]));
    sqf[i] = __fadd_rn(s0, s1);

    unsigned short* xrow = xh + (size_t)i * 64;
#pragma unroll
    for (int cb = 0; cb < 8; ++cb) {
        bf16x8 pk;
#pragma unroll
        for (int e = 0; e < 8; ++e) pk[e] = (short)bfr_(vr[cb * 8 + e]);
        *reinterpret_cast<bf16x8*>(xrow + ((cb ^ (n & 7)) * 8)) = pk;
    }
    if (xrT) {
        float4* dst = reinterpret_cast<float4*>(xrT + (size_t)i * C_);
#pragma unroll
        for (int q = 0; q < 16; ++q)
            dst[q] = make_float4(vr[q*4+0], vr[q*4+1], vr[q*4+2], vr[q*4+3]);
    }
}

// K3: Yt[b][m][o] = sum_c (W[o][c] - W[o][64+c]) * x[b][c][m]
__global__ __launch_bounds__(256) void k_y(const float* __restrict__ x,
                                           const float* __restrict__ W,
                                           float* __restrict__ Yt) {
    __shared__ float Al[C_ * 64];
    __shared__ float xl[C_ * 64];
    int tid = threadIdx.x;
    int bid = blockIdx.x;
    int b = bid >> 5;
    int m0 = (bid & 31) * 64;
    {
        int o = tid & 63, cb = tid >> 6;
#pragma unroll
        for (int j = 0; j < 16; ++j) {
            int c = cb * 16 + j;
            Al[c * 64 + o] = W[o * 128 + c] - W[o * 128 + 64 + c];
            xl[c * 64 + o] = x[((size_t)b * C_ + c) * N_ + m0 + o];
        }
    }
    __syncthreads();
    int ml = tid & 63, og = tid >> 6;
    float acc[16];
#pragma unroll
    for (int j = 0; j < 16; ++j) acc[j] = 0.f;
#pragma unroll 4
    for (int c = 0; c < C_; ++c) {
        float xv = xl[c * 64 + ml];
        const float4* a4 = reinterpret_cast<const float4*>(&Al[c * 64 + og * 16]);
#pragma unroll
        for (int q = 0; q < 4; ++q) {
            float4 av = a4[q];
            acc[q*4+0] = fmaf(av.x, xv, acc[q*4+0]);
            acc[q*4+1] = fmaf(av.y, xv, acc[q*4+1]);
            acc[q*4+2] = fmaf(av.z, xv, acc[q*4+2]);
            acc[q*4+3] = fmaf(av.w, xv, acc[q*4+3]);
        }
    }
    float* yp = Yt + ((size_t)b * N_ + m0 + ml) * C_ + og * 16;
#pragma unroll
    for (int q = 0; q < 4; ++q)
        reinterpret_cast<float4*>(yp)[q] =
            make_float4(acc[q*4+0], acc[q*4+1], acc[q*4+2], acc[q*4+3]);
}

// K2a: MFMA distance pass. 4 waves x 16 rows; A-frags in registers for the
// whole kernel; 8 m-tiles of 256 staged (linear copy of pre-swizzled bf16);
// per mb: 2 ds_read_b128 + 2 mfma -> dist -> sorted-insert into per-(lane,reg)
// top-12 lists. Extraction: 4 row-groups in parallel via width-16 shfl.
__global__ __launch_bounds__(256, 4) void k_dist(const unsigned short* __restrict__ xh,
                                                 const float* __restrict__ sqf,
                                                 unsigned* __restrict__ cand) {
    __shared__ __align__(16) unsigned short xtl[256 * 64];   // 32 KB
    __shared__ float sqm[256];
    int tid = threadIdx.x;
    int w = tid >> 6, lane = tid & 63;
    int bid = blockIdx.x;             // B_*32 = 512
    int b = bid >> 5;
    int n0 = (bid & 31) * 64;
    const unsigned short* xhb = xh + (size_t)b * N_ * 64;

    {   // stage 64 row-vectors (8 KB): linear coalesced copy (swizzle is in xh)
#pragma unroll
        for (int i = 0; i < 2; ++i) {
            int ch = tid + 256 * i;   // chunk of 8 ushorts
            *reinterpret_cast<uint4*>(&xtl[ch * 8]) =
                *reinterpret_cast<const uint4*>(&xhb[(size_t)n0 * 64 + ch * 8]);
        }
    }
    __syncthreads();
    int rl = w * 16 + (lane & 15);    // this lane's A-row (local)
    bf16x8 afr0, afr1;
    {
        int cb0 = (lane >> 4), cb1 = 4 + (lane >> 4);
        afr0 = *reinterpret_cast<const bf16x8*>(&xtl[rl * 64 + ((cb0 ^ (rl & 7)) * 8)]);
        afr1 = *reinterpret_cast<const bf16x8*>(&xtl[rl * 64 + ((cb1 ^ (rl & 7)) * 8)]);
    }
    float rsq[4];
#pragma unroll
    for (int r = 0; r < 4; ++r)
        rsq[r] = sqf[b * N_ + n0 + w * 16 + (lane >> 4) * 4 + r];

    unsigned list[4][LQ];
#pragma unroll
    for (int r = 0; r < 4; ++r)
#pragma unroll
        for (int j = 0; j < LQ; ++j) list[r][j] = 0xFFFFFFFFu;

    for (int t = 0; t < 8; ++t) {
        int m0 = t * 256;
        __syncthreads();
        {   // stage m-tile 256x64 bf16 (32 KB): linear coalesced copy
#pragma unroll
            for (int i = 0; i < 8; ++i) {
                int ch = tid + 256 * i;
                *reinterpret_cast<uint4*>(&xtl[ch * 8]) =
                    *reinterpret_cast<const uint4*>(&xhb[(size_t)m0 * 64 + ch * 8]);
            }
            sqm[tid] = sqf[b * N_ + m0 + tid];
        }
        __syncthreads();
#pragma unroll 4
        for (int mb = 0; mb < 16; ++mb) {
            int mloc = mb * 16 + (lane & 15);
            int cb0 = (lane >> 4), cb1 = 4 + (lane >> 4);
            bf16x8 bf0 = *reinterpret_cast<const bf16x8*>(
                &xtl[mloc * 64 + ((cb0 ^ (mloc & 7)) * 8)]);
            bf16x8 bf1 = *reinterpret_cast<const bf16x8*>(
                &xtl[mloc * 64 + ((cb1 ^ (mloc & 7)) * 8)]);
            f32x4 acc = {0.f, 0.f, 0.f, 0.f};
            acc = __builtin_amdgcn_mfma_f32_16x16x32_bf16(afr0, bf0, acc, 0, 0, 0);
            acc = __builtin_amdgcn_mfma_f32_16x16x32_bf16(afr1, bf1, acc, 0, 0, 0);
            float smv = sqm[mloc];
            unsigned mg = (unsigned)(m0 + mloc);
#pragma unroll
            for (int r = 0; r < 4; ++r) {
                float d = (rsq[r] + smv) - 2.f * acc[r];
                unsigned ub = __float_as_uint(d);
                unsigned mono = (ub & 0x80000000u) ? ~ub : (ub | 0x80000000u);
                unsigned key = (mono & 0xFFFFF800u) | mg;
#pragma unroll
                for (int j = LQ - 1; j > 0; --j)
                    list[r][j] = umin_(list[r][j], umax_(list[r][j - 1], key));
                list[r][0] = umin_(list[r][0], key);
            }
        }
    }

    // extraction: 4 row-groups (16 lanes each) extract their 4 rows in
    // parallel; keys unique (low 11 bits = m, m%16 = lane&15).
#pragma unroll
    for (int j = 0; j < 4; ++j) {
        size_t grow = (size_t)b * N_ + n0 + w * 16 + (lane >> 4) * 4 + j;
#pragma unroll 1
        for (int it = 0; it < CAND; ++it) {
            unsigned head = list[j][0];
            unsigned wv = head;
            wv = umin_(wv, (unsigned)__shfl_xor((int)wv, 1, 16));
            wv = umin_(wv, (unsigned)__shfl_xor((int)wv, 2, 16));
            wv = umin_(wv, (unsigned)__shfl_xor((int)wv, 4, 16));
            wv = umin_(wv, (unsigned)__shfl_xor((int)wv, 8, 16));
            bool own = (head == wv);
#pragma unroll
            for (int jj = 0; jj < LQ - 1; ++jj)
                list[j][jj] = own ? list[j][jj + 1] : list[j][jj];
            list[j][LQ - 1] = own ? 0xFFFFFFFFu : list[j][LQ - 1];
            if ((lane & 15) == 0) cand[grow * CAND + it] = wv & 2047u;
        }
    }
}

// K2b: exact numpy-f32 rescore (sequential c, separate mul/add) + stable rank.
// Contiguous xrT rows when workspace allows; strided x fallback (both forms
// bit-identical to the round-3-proven pipeline).
__global__ __launch_bounds__(256) void k_rescore(const float* __restrict__ x,
                                                 const float* __restrict__ xrT,
                                                 const float* __restrict__ sqf,
                                                 const unsigned* __restrict__ cand,
                                                 float* __restrict__ idxf) {
    int tid = threadIdx.x;
    int w = tid >> 6, lane = tid & 63;
    size_t grow = (size_t)blockIdx.x * 4 + w;   // 0..32767
    int b = (int)(grow >> 11), n = (int)(grow & (N_ - 1));
    float d = 0.f;
    unsigned m = 0xFFFFFFFFu;
    if (xrT) {
        const float* xr = xrT + (size_t)b * N_ * C_;
        const float* xn = xr + (size_t)n * C_;
        if (lane < CAND) {
            m = cand[grow * CAND + lane];
            const float* xm = xr + (size_t)m * C_;
            float a = 0.f;
#pragma unroll 8
            for (int c = 0; c < C_; ++c)
                a = __fadd_rn(a, __fmul_rn(xn[c], xm[c]));
            d = __fadd_rn(__fsub_rn(sqf[b * N_ + n], __fmul_rn(2.0f, a)), sqf[b * N_ + m]);
        }
    } else {
        const float* xb = x + (size_t)b * C_ * N_;
        if (lane < CAND) {
            m = cand[grow * CAND + lane];
            float a = 0.f;
#pragma unroll 8
            for (int c = 0; c < C_; ++c)
                a = __fadd_rn(a, __fmul_rn(xb[(size_t)c * N_ + n], xb[(size_t)c * N_ + m]));
            d = __fadd_rn(__fsub_rn(sqf[b * N_ + n], __fmul_rn(2.0f, a)), sqf[b * N_ + m]);
        }
    }
    int rank = 0;
#pragma unroll 1
    for (int j = 0; j < CAND; ++j) {
        float dj = __shfl(d, j, 64);
        unsigned mj = (unsigned)__shfl((int)m, j, 64);
        if (lane < CAND && (dj < d || (dj == d && mj < m))) ++rank;
    }
    if (lane < CAND && rank < K_)
        idxf[grow * K_ + rank] = (float)m;
}

// K4: out[b][o][n] = leaky( s[o]*(u + max_k Yt[b][idx[n][k]][o]) + t[o] )
__global__ __launch_bounds__(256) void k_out(const float* __restrict__ x,
                                             const float* __restrict__ W,
                                             const float* __restrict__ gamma,
                                             const float* __restrict__ beta,
                                             const float* __restrict__ rmean,
                                             const float* __restrict__ rvar,
                                             const float* __restrict__ Yt,
                                             const float* __restrict__ idxf,
                                             float* __restrict__ out) {
    __shared__ float Bl[C_ * 64];
    __shared__ float xl[C_ * 64];
    __shared__ float resl[64 * 65];
    __shared__ float sl[64], tl[64];
    int tid = threadIdx.x;
    int bid = blockIdx.x;
    int b = bid >> 5;
    int n0 = (bid & 31) * 64;
    {
        int o = tid & 63, cb = tid >> 6;
#pragma unroll
        for (int j = 0; j < 16; ++j) {
            int c = cb * 16 + j;
            Bl[c * 64 + o] = W[o * 128 + 64 + c];
            xl[c * 64 + o] = x[((size_t)b * C_ + c) * N_ + n0 + o];
        }
        if (tid < 64) {
            float s = gamma[tid] / sqrtf(rvar[tid] + 1e-5f);
            sl[tid] = s;
            tl[tid] = beta[tid] - rmean[tid] * s;
        }
    }
    __syncthreads();
    int w = tid >> 6, o = tid & 63;
    for (int i = 0; i < 16; ++i) {
        int nl = w * 16 + i;
        int n = n0 + nl;
        float u = 0.f;
#pragma unroll 8
        for (int c = 0; c < C_; ++c)
            u = fmaf(Bl[c * 64 + o], xl[c * 64 + nl], u);
        const float* ip = idxf + ((size_t)b * N_ + n) * K_;
        float v = -3.4e38f;
#pragma unroll
        for (int k = 0; k < K_; ++k) {
            int mi = (int)ip[k];
            v = fmaxf(v, Yt[((size_t)b * N_ + mi) * C_ + o]);
        }
        float h = u + v;
        float val = sl[o] * h + tl[o];
        val = val > 0.f ? val : 0.2f * val;
        resl[o * 65 + nl] = val;
    }
    __syncthreads();
    {
        int nl = tid & 63, ob = tid >> 6;
#pragma unroll
        for (int j = 0; j < 16; ++j) {
            int o2 = ob * 16 + j;
            out[((size_t)b * C_ + o2) * N_ + n0 + nl] = resl[o2 * 65 + nl];
        }
    }
}

extern "C" void kernel_launch(void* const* d_in, const int* in_sizes, int n_in,
                              void* d_out, int out_size, void* d_ws, size_t ws_size,
                              hipStream_t stream) {
    const float* x     = (const float*)d_in[0];
    const float* W     = (const float*)d_in[1];
    const float* gamma = (const float*)d_in[2];
    const float* beta  = (const float*)d_in[3];
    const float* rmean = (const float*)d_in[4];
    const float* rvar  = (const float*)d_in[5];

    float* out  = (float*)d_out;                         // [16][64][2048]
    float* idxf = out + (size_t)B_ * C_ * N_;            // [16][2048][20] as floats

    char* ws            = (char*)d_ws;
    float* sqf          = (float*)ws;                              // 128 KB
    unsigned* cand      = (unsigned*)(ws + 131072);                // 3.0 MB
    unsigned short* xh  = (unsigned short*)(ws + 131072 + 3145728);// 4 MB
    size_t need_xrT     = (size_t)131072 + 3145728 + 4194304 + 8388608;
    float* xrT          = (ws_size >= need_xrT)
                        ? (float*)(ws + 131072 + 3145728 + 4194304) : nullptr;
    // Yt (8 MB) aliases cand+xh (+head of xrT): all dead before k_y runs.
    float* Yt           = (float*)(ws + 131072);

    k_sq     <<<B_ * N_ / 128, 128, 0, stream>>>(x, sqf, xh, xrT);
    k_dist   <<<B_ * 32, 256, 0, stream>>>(xh, sqf, cand);
    k_rescore<<<B_ * N_ / 4, 256, 0, stream>>>(x, xrT, sqf, cand, idxf);
    k_y      <<<B_ * (N_ / 64), 256, 0, stream>>>(x, W, Yt);
    k_out    <<<B_ * (N_ / 64), 256, 0, stream>>>(x, W, gamma, beta, rmean, rvar, Yt, idxf, out);
}